// Round 13
// baseline (193.571 us; speedup 1.0000x reference)
//
#include <hip/hip_runtime.h>
#include <cstdint>
#include <cstddef>

using u16 = unsigned short;
using u8  = unsigned char;
typedef short short8 __attribute__((ext_vector_type(8)));
typedef __bf16 bf16x8 __attribute__((ext_vector_type(8)));
typedef float f32x4 __attribute__((ext_vector_type(4)));
typedef u16 u16x4 __attribute__((ext_vector_type(4)));
typedef int i32x4 __attribute__((ext_vector_type(4)));
typedef int i32x8 __attribute__((ext_vector_type(8)));

__device__ __forceinline__ u16 f2bf(float f) {
  union { float f; uint32_t u; } v; v.f = f;
  uint32_t r = v.u + 0x7FFF + ((v.u >> 16) & 1);
  return (u16)(r >> 16);
}
__device__ __forceinline__ u8 f2fp8(float f) {
  return (u8)(__builtin_amdgcn_cvt_pk_fp8_f32(f, f, 0, 0) & 0xFF);
}

__device__ __forceinline__ void gload16(const void* g, void* l) {
  __builtin_amdgcn_global_load_lds(
      (const __attribute__((address_space(1))) void*)g,
      (__attribute__((address_space(3))) void*)l, 16, 0, 0);
}

// =====================================================================
// MX-fp8 GEMM skeleton (R9, proven): 256x256 tile, BK=128B, NT=8,
// 8 waves (2x4), one-phase-ahead reads, counted lgkm/vmcnt, 3 barriers
// per K-tile, XCD-bijective swizzle. Shared by the MLP GEMMs and sim.
// =====================================================================
#define MFMAQ8(M0, N0, AF, BF)                                             \
  {                                                                        \
    _Pragma("unroll") for (int m_ = 0; m_ < 4; ++m_) {                     \
      _Pragma("unroll") for (int n_ = 0; n_ < 2; ++n_) {                   \
        acc[(M0) + m_][(N0) + n_] =                                        \
            __builtin_amdgcn_mfma_scale_f32_16x16x128_f8f6f4(              \
                AF[m_], BF[n_], acc[(M0) + m_][(N0) + n_],                 \
                0, 0, 0, 127, 0, 127);                                     \
      }                                                                    \
    }                                                                      \
  }

// Core K-loop as a macro-free inline: fills acc for tile (arow0, brow0).
// A,B are u8[*][1024] row-major fp8.
__device__ __forceinline__ void fp8_core(
    const u8* __restrict__ A, const u8* __restrict__ Bt,
    int arow0, int brow0, u8* lds, f32x4 (&acc)[8][4],
    int lane, int wid, int wr, int wc, int li)
{
  constexpr int Kb = 1024, NT = 8;
  const int Rl = lane >> 3;
  const int sc16 = ((lane & 7) ^ Rl) << 4;
  const int wid2 = wid * 2;
  const int hk = lane >> 4;
  const int c0b = (((hk << 1) + 0) ^ (li & 7)) << 4;
  const int c1b = (((hk << 1) + 1) ^ (li & 7)) << 4;

  auto STAGE = [&](const u8* G, int growbase, int tau, int ldsoff) {
#pragma unroll
    for (int l = 0; l < 2; ++l) {
      const u8* g = G + (size_t)(growbase + (wid2 + l) * 8 + Rl) * Kb +
                    tau * 128 + sc16;
      gload16(g, lds + ldsoff + (wid2 + l) * 1024);
    }
  };
  auto RD = [&](const u8* base, int row) -> i32x8 {
    const u8* p = base + row * 128;
    i32x4 lo = *reinterpret_cast<const i32x4*>(p + c0b);
    i32x4 hi = *reinterpret_cast<const i32x4*>(p + c1b);
    i32x8 r;
    r[0] = lo[0]; r[1] = lo[1]; r[2] = lo[2]; r[3] = lo[3];
    r[4] = hi[0]; r[5] = hi[1]; r[6] = hi[2]; r[7] = hi[3];
    return r;
  };

  i32x8 aa[4], bb01[2], bb23[2];

  STAGE(Bt, brow0 + 0,   0, 65536 + 0);
  STAGE(Bt, brow0 + 128, 0, 65536 + 16384);
  STAGE(A,  arow0 + 0,   0, 0);
  STAGE(A,  arow0 + 128, 0, 16384);
  STAGE(Bt, brow0 + 0,   1, 65536 + 32768);
  STAGE(Bt, brow0 + 128, 1, 65536 + 32768 + 16384);
  STAGE(A,  arow0 + 0,   1, 32768);
  STAGE(A,  arow0 + 128, 1, 32768 + 16384);
  asm volatile("s_waitcnt vmcnt(8)" ::: "memory");
  __builtin_amdgcn_s_barrier();

  {
    const u8* Ab0 = lds + wr * 16384;
    const u8* Bb0 = lds + 65536 + wc * 8192;
#pragma unroll
    for (int m = 0; m < 4; ++m) aa[m] = RD(Ab0, m * 16 + li);
#pragma unroll
    for (int n = 0; n < 2; ++n) bb01[n] = RD(Bb0, n * 16 + li);
  }

  for (int tau = 0; tau < NT; ++tau) {
    const int cur = tau & 1, nxt = cur ^ 1;
    const u8* Ab  = lds + cur * 32768 + wr * 16384;
    const u8* Bb  = lds + 65536 + cur * 32768 + wc * 8192;
    const u8* Abn = lds + nxt * 32768 + wr * 16384;
    const u8* Bbn = lds + 65536 + nxt * 32768 + wc * 8192;

#pragma unroll
    for (int n = 0; n < 2; ++n) bb23[n] = RD(Bb, 32 + n * 16 + li);
    asm volatile("s_waitcnt lgkmcnt(4)" ::: "memory");
    __builtin_amdgcn_sched_barrier(0);
    __builtin_amdgcn_s_setprio(1);
    MFMAQ8(0, 0, aa, bb01);
    __builtin_amdgcn_s_setprio(0);

    asm volatile("s_waitcnt lgkmcnt(0)" ::: "memory");
    __builtin_amdgcn_sched_barrier(0);
    __builtin_amdgcn_s_setprio(1);
    MFMAQ8(0, 2, aa, bb23);
    __builtin_amdgcn_s_setprio(0);
    __builtin_amdgcn_sched_barrier(0);
#pragma unroll
    for (int m = 0; m < 4; ++m) aa[m] = RD(Ab, (m + 4) * 16 + li);
    __builtin_amdgcn_s_barrier();

    if (tau + 2 < NT) {
      STAGE(Bt, brow0 + 0,   tau + 2, 65536 + cur * 32768);
      STAGE(Bt, brow0 + 128, tau + 2, 65536 + cur * 32768 + 16384);
    }
    asm volatile("s_waitcnt lgkmcnt(0)" ::: "memory");
    __builtin_amdgcn_sched_barrier(0);
    __builtin_amdgcn_s_setprio(1);
    MFMAQ8(4, 2, aa, bb23);
    __builtin_amdgcn_s_setprio(0);
    __builtin_amdgcn_s_barrier();

    if (tau + 2 < NT) {
      STAGE(A, arow0 + 0,   tau + 2, cur * 32768);
      STAGE(A, arow0 + 128, tau + 2, cur * 32768 + 16384);
      asm volatile("s_waitcnt vmcnt(8)" ::: "memory");
    } else if (tau + 1 < NT) {
      asm volatile("s_waitcnt vmcnt(0)" ::: "memory");
    }
    __builtin_amdgcn_s_barrier();
    __builtin_amdgcn_s_setprio(1);
    MFMAQ8(4, 0, aa, bb01);
    __builtin_amdgcn_s_setprio(0);
    __builtin_amdgcn_sched_barrier(0);
    if (tau + 1 < NT) {
#pragma unroll
      for (int m = 0; m < 4; ++m) aa[m] = RD(Abn, m * 16 + li);
#pragma unroll
      for (int n = 0; n < 2; ++n) bb01[n] = RD(Bbn, n * 16 + li);
    }
  }
}

// ---------------- MLP GEMM (fp8): relu(acc/512 + b) ----------------
template <int EPI>
__global__ __launch_bounds__(512, 2) void gemm_fp8(
    const u8* __restrict__ A, const u8* __restrict__ Bt,
    const float* __restrict__ bias,
    u8* __restrict__ C8, float* __restrict__ Cf)
{
  constexpr int N = 1024;
  __shared__ alignas(16) u8 lds[131072];
  const int t = (int)threadIdx.x;
  const int lane = t & 63, wid = t >> 6;
  const int wr = wid >> 2, wc = wid & 3;
  const int li = lane & 15, hk = lane >> 4;

  const int orig = (int)blockIdx.x;
  const int cpx = (int)gridDim.x >> 3;
  const int swz = (orig & 7) * cpx + (orig >> 3);
  const int bm = swz >> 2, bn = swz & 3;
  const int arow0 = bm * 256, brow0 = bn * 256;

  f32x4 acc[8][4];
#pragma unroll
  for (int m = 0; m < 8; ++m)
#pragma unroll
    for (int n = 0; n < 4; ++n)
#pragma unroll
      for (int j = 0; j < 4; ++j) acc[m][n][j] = 0.0f;

  fp8_core(A, Bt, arow0, brow0, lds, acc, lane, wid, wr, wc, li);

#pragma unroll
  for (int m = 0; m < 8; ++m) {
#pragma unroll
    for (int n = 0; n < 4; ++n) {
      const int gcol = brow0 + wc * 64 + n * 16 + li;
      const float bv = bias[gcol];
#pragma unroll
      for (int j = 0; j < 4; ++j) {
        const int grow = arow0 + wr * 128 + m * 16 + hk * 4 + j;
        float v = fmaxf(acc[m][n][j] * 0.001953125f + bv, 0.0f);
        if (EPI == 0) {
          C8[(size_t)grow * N + gcol] = f2fp8(v * 8.0f);
        } else {
          int tensor = grow >> 13, rr = grow & 8191;
          int tt = rr >> 3, b_ = rr & 7;
          Cf[(size_t)tensor * 8388608 + (size_t)b_ * 1048576 +
             (size_t)tt * 1024 + gcol] = v;
        }
      }
    }
  }
}

// ---------------- sim GEMM (fp8 Gram): S[m] += w*exp(10*G); dots fold ----
// Z8 = fp8(z*16) -> G = acc/256. Grid 64 blocks (8x8 of 256^2).
__global__ __launch_bounds__(512, 2) void sim_fp8(
    const u8* __restrict__ Z8, float* __restrict__ S, float* __restrict__ dots)
{
  __shared__ alignas(16) u8 lds[131072];
  const int t = (int)threadIdx.x;
  const int lane = t & 63, wid = t >> 6;
  const int wr = wid >> 2, wc = wid & 3;
  const int li = lane & 15, hk = lane >> 4;

  const int orig = (int)blockIdx.x;           // 64 blocks
  const int swz = (orig & 7) * 8 + (orig >> 3);
  const int bm = swz >> 3, bn = swz & 7;
  const int arow0 = bm * 256, brow0 = bn * 256;

  f32x4 acc[8][4];
#pragma unroll
  for (int m = 0; m < 8; ++m)
#pragma unroll
    for (int n = 0; n < 4; ++n)
#pragma unroll
      for (int j = 0; j < 4; ++j) acc[m][n][j] = 0.0f;

  fp8_core(Z8, Z8, arow0, brow0, lds, acc, lane, wid, wr, wc, li);

  float dsum = 0.0f;
#pragma unroll
  for (int m = 0; m < 8; ++m) {
#pragma unroll
    for (int j = 0; j < 4; ++j) {
      const int grow = arow0 + wr * 128 + m * 16 + hk * 4 + j;
      float s = 0.0f;
#pragma unroll
      for (int n = 0; n < 4; ++n) {
        const int gcol = brow0 + wc * 64 + n * 16 + li;
        const float g = acc[m][n][j] * 0.00390625f;   // /256
        float logit = (grow == gcol) ? 10.0f : g * 10.0f;
        float w = (gcol == 0 || gcol == 1023 || gcol == 1024 || gcol == 2047)
                      ? 1.0f : 2.0f;
        s += w * expf(logit);
        if (gcol == grow + 1 && (grow & 1023) != 1023) dsum += g;
      }
      s += __shfl_xor(s, 1); s += __shfl_xor(s, 2);
      s += __shfl_xor(s, 4); s += __shfl_xor(s, 8);
      if (li == 0) atomicAdd(&S[grow], s);
    }
  }
#pragma unroll
  for (int d = 1; d < 64; d <<= 1) dsum += __shfl_xor(dsum, d);
  if (lane == 0) atomicAdd(dots, dsum);
}

// ---------------- fused prep: convert_x(fp8,x8) + transpose W(fp8,x64) + zero S
__global__ void prep_kernel(const float* __restrict__ h1,
                            const float* __restrict__ h2,
                            const float* __restrict__ W1,
                            const float* __restrict__ W2,
                            u8* __restrict__ X8,
                            u8* __restrict__ W1t,
                            u8* __restrict__ W2t,
                            float* __restrict__ S)
{
  __shared__ float tile[32][33];
  int bid = (int)blockIdx.x;
  if (bid < 16384) {
    size_t i4 = ((size_t)bid * 256 + threadIdx.x) * 4;
    const float* src = (i4 < 8388608) ? (h1 + i4) : (h2 + (i4 - 8388608));
    float4 v = *reinterpret_cast<const float4*>(src);
    int lo = __builtin_amdgcn_cvt_pk_fp8_f32(v.x * 8.0f, v.y * 8.0f, 0, 0);
    int all4 = __builtin_amdgcn_cvt_pk_fp8_f32(v.z * 8.0f, v.w * 8.0f, lo, 1);
    *reinterpret_cast<uint32_t*>(X8 + i4) = (uint32_t)all4;
    return;
  }
  bid -= 16384;
  const float* W;
  u8* Wt;
  if (bid < 1024) {
    W = W1; Wt = W1t;
  } else if (bid < 2048) {
    W = W2; Wt = W2t; bid -= 1024;
  } else {
    for (int i = (int)threadIdx.x; i < 2064; i += 256) S[i] = 0.0f;
    return;
  }
  const int bx = bid & 31, by = bid >> 5;
  const int tx = (int)threadIdx.x & 31, ty = (int)threadIdx.x >> 5;
#pragma unroll
  for (int i = 0; i < 4; ++i)
    tile[ty + i * 8][tx] = W[(size_t)(by * 32 + ty + i * 8) * 1024 + bx * 32 + tx];
  __syncthreads();
#pragma unroll
  for (int i = 0; i < 4; ++i)
    Wt[(size_t)(bx * 32 + ty + i * 8) * 1024 + by * 32 + tx] =
        f2fp8(tile[tx][ty + i * 8] * 64.0f);
}

// ---------------- row_normalize: out rows -> fp8 z*16 ----------------
__global__ void row_normalize(const float* __restrict__ out, u8* __restrict__ Z8)
{
  const int row = (int)blockIdx.x;   // 0..2047
  const int t = (int)threadIdx.x;    // 256
  const float* src = out + ((row < 1024)
      ? ((size_t)7 * 1048576 + (size_t)row * 1024)
      : ((size_t)8388608 + (size_t)7 * 1048576 + (size_t)(row - 1024) * 1024));
  float4 v = reinterpret_cast<const float4*>(src)[t];
  float ss = v.x * v.x + v.y * v.y + v.z * v.z + v.w * v.w;
#pragma unroll
  for (int d = 1; d < 64; d <<= 1) ss += __shfl_xor(ss, d);
  __shared__ float red[4];
  if ((t & 63) == 0) red[t >> 6] = ss;
  __syncthreads();
  float tot = red[0] + red[1] + red[2] + red[3];
  float inv = 16.0f / fmaxf(sqrtf(tot), 1e-12f);   // fp8 scale x16 folded in
  int lo = __builtin_amdgcn_cvt_pk_fp8_f32(v.x * inv, v.y * inv, 0, 0);
  int all4 = __builtin_amdgcn_cvt_pk_fp8_f32(v.z * inv, v.w * inv, lo, 1);
  reinterpret_cast<uint32_t*>(Z8 + (size_t)row * 1024)[t] = (uint32_t)all4;
}

__global__ void finalize_kernel(const float* __restrict__ S,
                                const float* __restrict__ dots,
                                float* __restrict__ out_loss)
{
  const int t = (int)threadIdx.x;  // 256
  float acc = 0.0f;
  for (int i = t; i < 2048; i += 256) {
    int tl = i & 1023;
    float w = (tl == 0 || tl == 1023) ? 1.0f : 2.0f;
    acc += w * logf(S[i] - 22026.465794806718f);
  }
  __shared__ float red[256];
  red[t] = acc;
  __syncthreads();
  for (int s2 = 128; s2 > 0; s2 >>= 1) {
    if (t < s2) red[t] += red[t + s2];
    __syncthreads();
  }
  if (t == 0) out_loss[0] = (red[0] - 20.0f * dots[0]) / 4092.0f;
}

extern "C" void kernel_launch(void* const* d_in, const int* in_sizes, int n_in,
                              void* d_out, int out_size, void* d_ws, size_t ws_size,
                              hipStream_t stream)
{
  const float* h1 = (const float*)d_in[0];
  const float* h2 = (const float*)d_in[1];
  const float* W1 = (const float*)d_in[2];
  const float* b1 = (const float*)d_in[3];
  const float* W2 = (const float*)d_in[4];
  const float* b2 = (const float*)d_in[5];
  float* out = (float*)d_out;

  char* ws = (char*)d_ws;
  u8*    X8   = (u8*)ws;                       // 16,777,216 B (fp8, x8)
  u8*    Y18  = (u8*)(ws + 16777216);          // 16,777,216 B (fp8, x8)
  u8*    W1t  = (u8*)(ws + 33554432);          //  1,048,576 B (fp8, x64)
  u8*    W2t  = (u8*)(ws + 34603008);          //  1,048,576 B (fp8, x64)
  u8*    Z8   = (u8*)(ws + 35651584);          //  2,097,152 B (fp8, x16)
  float* S    = (float*)(ws + 37748736);       //      8,192 B (+dots at S[2048])
  float* dots = S + 2048;

  // fused: convert_x (16384 blocks) + transpose W1/W2 (2048) + zero S (1)
  prep_kernel<<<18433, 256, 0, stream>>>(h1, h2, W1, W2, X8, W1t, W2t, S);

  // layer 1: [16384,1024] @ W1 -> relu -> fp8 (256 blocks, 512 thr, MX-fp8)
  gemm_fp8<0><<<256, 512, 0, stream>>>(X8, W1t, b1, Y18, nullptr);
  // layer 2: -> relu -> fp32, transposed write into d_out ([b][t][h])
  gemm_fp8<1><<<256, 512, 0, stream>>>(Y18, W2t, b2, nullptr, out);

  // InfoNCE on last batch row: fp8 Gram via the same proven GEMM skeleton
  row_normalize<<<2048, 256, 0, stream>>>(out, Z8);
  sim_fp8<<<64, 512, 0, stream>>>(Z8, S, dots);
  finalize_kernel<<<1, 256, 0, stream>>>(S, dots, out + 16777216);
}

// Round 14
// 108.786 us; speedup vs baseline: 1.7794x; 1.7794x over previous
//
#include <hip/hip_runtime.h>
#include <cstdint>
#include <cstddef>

using u16 = unsigned short;
using u8  = unsigned char;
typedef short short8 __attribute__((ext_vector_type(8)));
typedef __bf16 bf16x8 __attribute__((ext_vector_type(8)));
typedef float f32x4 __attribute__((ext_vector_type(4)));
typedef u16 u16x4 __attribute__((ext_vector_type(4)));
typedef int i32x4 __attribute__((ext_vector_type(4)));
typedef int i32x8 __attribute__((ext_vector_type(8)));

__device__ __forceinline__ u16 f2bf(float f) {
  union { float f; uint32_t u; } v; v.f = f;
  uint32_t r = v.u + 0x7FFF + ((v.u >> 16) & 1);
  return (u16)(r >> 16);
}
__device__ __forceinline__ float bf2f(u16 b) {
  union { uint32_t u; float f; } v; v.u = ((uint32_t)b) << 16;
  return v.f;
}
__device__ __forceinline__ u8 f2fp8(float f) {
  return (u8)(__builtin_amdgcn_cvt_pk_fp8_f32(f, f, 0, 0) & 0xFF);
}

__device__ __forceinline__ void gload16(const void* g, void* l) {
  __builtin_amdgcn_global_load_lds(
      (const __attribute__((address_space(1))) void*)g,
      (__attribute__((address_space(3))) void*)l, 16, 0, 0);
}

// =====================================================================
// MX-fp8 GEMM skeleton (R9/R13, proven ~22us & simple epilogue only —
// complex epilogues on this 128-AGPR accumulator spill, R13 lesson).
// =====================================================================
#define MFMAQ8(M0, N0, AF, BF)                                             \
  {                                                                        \
    _Pragma("unroll") for (int m_ = 0; m_ < 4; ++m_) {                     \
      _Pragma("unroll") for (int n_ = 0; n_ < 2; ++n_) {                   \
        acc[(M0) + m_][(N0) + n_] =                                        \
            __builtin_amdgcn_mfma_scale_f32_16x16x128_f8f6f4(              \
                AF[m_], BF[n_], acc[(M0) + m_][(N0) + n_],                 \
                0, 0, 0, 127, 0, 127);                                     \
      }                                                                    \
    }                                                                      \
  }

__device__ __forceinline__ void fp8_core(
    const u8* __restrict__ A, const u8* __restrict__ Bt,
    int arow0, int brow0, u8* lds, f32x4 (&acc)[8][4],
    int lane, int wid, int wr, int wc, int li)
{
  constexpr int Kb = 1024, NT = 8;
  const int Rl = lane >> 3;
  const int sc16 = ((lane & 7) ^ Rl) << 4;
  const int wid2 = wid * 2;
  const int hk = lane >> 4;
  const int c0b = (((hk << 1) + 0) ^ (li & 7)) << 4;
  const int c1b = (((hk << 1) + 1) ^ (li & 7)) << 4;

  auto STAGE = [&](const u8* G, int growbase, int tau, int ldsoff) {
#pragma unroll
    for (int l = 0; l < 2; ++l) {
      const u8* g = G + (size_t)(growbase + (wid2 + l) * 8 + Rl) * Kb +
                    tau * 128 + sc16;
      gload16(g, lds + ldsoff + (wid2 + l) * 1024);
    }
  };
  auto RD = [&](const u8* base, int row) -> i32x8 {
    const u8* p = base + row * 128;
    i32x4 lo = *reinterpret_cast<const i32x4*>(p + c0b);
    i32x4 hi = *reinterpret_cast<const i32x4*>(p + c1b);
    i32x8 r;
    r[0] = lo[0]; r[1] = lo[1]; r[2] = lo[2]; r[3] = lo[3];
    r[4] = hi[0]; r[5] = hi[1]; r[6] = hi[2]; r[7] = hi[3];
    return r;
  };

  i32x8 aa[4], bb01[2], bb23[2];

  STAGE(Bt, brow0 + 0,   0, 65536 + 0);
  STAGE(Bt, brow0 + 128, 0, 65536 + 16384);
  STAGE(A,  arow0 + 0,   0, 0);
  STAGE(A,  arow0 + 128, 0, 16384);
  STAGE(Bt, brow0 + 0,   1, 65536 + 32768);
  STAGE(Bt, brow0 + 128, 1, 65536 + 32768 + 16384);
  STAGE(A,  arow0 + 0,   1, 32768);
  STAGE(A,  arow0 + 128, 1, 32768 + 16384);
  asm volatile("s_waitcnt vmcnt(8)" ::: "memory");
  __builtin_amdgcn_s_barrier();

  {
    const u8* Ab0 = lds + wr * 16384;
    const u8* Bb0 = lds + 65536 + wc * 8192;
#pragma unroll
    for (int m = 0; m < 4; ++m) aa[m] = RD(Ab0, m * 16 + li);
#pragma unroll
    for (int n = 0; n < 2; ++n) bb01[n] = RD(Bb0, n * 16 + li);
  }

  for (int tau = 0; tau < NT; ++tau) {
    const int cur = tau & 1, nxt = cur ^ 1;
    const u8* Ab  = lds + cur * 32768 + wr * 16384;
    const u8* Bb  = lds + 65536 + cur * 32768 + wc * 8192;
    const u8* Abn = lds + nxt * 32768 + wr * 16384;
    const u8* Bbn = lds + 65536 + nxt * 32768 + wc * 8192;

#pragma unroll
    for (int n = 0; n < 2; ++n) bb23[n] = RD(Bb, 32 + n * 16 + li);
    asm volatile("s_waitcnt lgkmcnt(4)" ::: "memory");
    __builtin_amdgcn_sched_barrier(0);
    __builtin_amdgcn_s_setprio(1);
    MFMAQ8(0, 0, aa, bb01);
    __builtin_amdgcn_s_setprio(0);

    asm volatile("s_waitcnt lgkmcnt(0)" ::: "memory");
    __builtin_amdgcn_sched_barrier(0);
    __builtin_amdgcn_s_setprio(1);
    MFMAQ8(0, 2, aa, bb23);
    __builtin_amdgcn_s_setprio(0);
    __builtin_amdgcn_sched_barrier(0);
#pragma unroll
    for (int m = 0; m < 4; ++m) aa[m] = RD(Ab, (m + 4) * 16 + li);
    __builtin_amdgcn_s_barrier();

    if (tau + 2 < NT) {
      STAGE(Bt, brow0 + 0,   tau + 2, 65536 + cur * 32768);
      STAGE(Bt, brow0 + 128, tau + 2, 65536 + cur * 32768 + 16384);
    }
    asm volatile("s_waitcnt lgkmcnt(0)" ::: "memory");
    __builtin_amdgcn_sched_barrier(0);
    __builtin_amdgcn_s_setprio(1);
    MFMAQ8(4, 2, aa, bb23);
    __builtin_amdgcn_s_setprio(0);
    __builtin_amdgcn_s_barrier();

    if (tau + 2 < NT) {
      STAGE(A, arow0 + 0,   tau + 2, cur * 32768);
      STAGE(A, arow0 + 128, tau + 2, cur * 32768 + 16384);
      asm volatile("s_waitcnt vmcnt(8)" ::: "memory");
    } else if (tau + 1 < NT) {
      asm volatile("s_waitcnt vmcnt(0)" ::: "memory");
    }
    __builtin_amdgcn_s_barrier();
    __builtin_amdgcn_s_setprio(1);
    MFMAQ8(4, 0, aa, bb01);
    __builtin_amdgcn_s_setprio(0);
    __builtin_amdgcn_sched_barrier(0);
    if (tau + 1 < NT) {
#pragma unroll
      for (int m = 0; m < 4; ++m) aa[m] = RD(Abn, m * 16 + li);
#pragma unroll
      for (int n = 0; n < 2; ++n) bb01[n] = RD(Bbn, n * 16 + li);
    }
  }
}

// ---------------- MLP GEMM (fp8): relu(acc/512 + b) ----------------
template <int EPI>
__global__ __launch_bounds__(512, 2) void gemm_fp8(
    const u8* __restrict__ A, const u8* __restrict__ Bt,
    const float* __restrict__ bias,
    u8* __restrict__ C8, float* __restrict__ Cf)
{
  constexpr int N = 1024;
  __shared__ alignas(16) u8 lds[131072];
  const int t = (int)threadIdx.x;
  const int lane = t & 63, wid = t >> 6;
  const int wr = wid >> 2, wc = wid & 3;
  const int li = lane & 15, hk = lane >> 4;

  const int orig = (int)blockIdx.x;
  const int cpx = (int)gridDim.x >> 3;
  const int swz = (orig & 7) * cpx + (orig >> 3);
  const int bm = swz >> 2, bn = swz & 3;
  const int arow0 = bm * 256, brow0 = bn * 256;

  f32x4 acc[8][4];
#pragma unroll
  for (int m = 0; m < 8; ++m)
#pragma unroll
    for (int n = 0; n < 4; ++n)
#pragma unroll
      for (int j = 0; j < 4; ++j) acc[m][n][j] = 0.0f;

  fp8_core(A, Bt, arow0, brow0, lds, acc, lane, wid, wr, wc, li);

#pragma unroll
  for (int m = 0; m < 8; ++m) {
#pragma unroll
    for (int n = 0; n < 4; ++n) {
      const int gcol = brow0 + wc * 64 + n * 16 + li;
      const float bv = bias[gcol];
#pragma unroll
      for (int j = 0; j < 4; ++j) {
        const int grow = arow0 + wr * 128 + m * 16 + hk * 4 + j;
        float v = fmaxf(acc[m][n][j] * 0.001953125f + bv, 0.0f);
        if (EPI == 0) {
          C8[(size_t)grow * N + gcol] = f2fp8(v * 8.0f);
        } else {
          int tensor = grow >> 13, rr = grow & 8191;
          int tt = rr >> 3, b_ = rr & 7;
          Cf[(size_t)tensor * 8388608 + (size_t)b_ * 1048576 +
             (size_t)tt * 1024 + gcol] = v;
        }
      }
    }
  }
}

// =====================================================================
// 128x128 bf16 core (R1/R9, proven, 0 bank conflicts) — sim only.
// =====================================================================
__device__ __forceinline__ void gemm_core_128(
    const u16* __restrict__ A, const u16* __restrict__ B,
    int arow0, int brow0, int K,
    u16* As, u16* Bs, f32x4 (&acc)[4][4])
{
  const int t = (int)threadIdx.x;
  const int lane = t & 63, wv = t >> 6;
  const int wr = wv >> 1, wc = wv & 1;
  const int li = lane & 15, hk = lane >> 4;
  const int sr = t >> 3, sc = t & 7;

#pragma unroll
  for (int m = 0; m < 4; ++m)
#pragma unroll
    for (int n = 0; n < 4; ++n)
#pragma unroll
      for (int j = 0; j < 4; ++j) acc[m][n][j] = 0.0f;

  for (int kt = 0; kt < K; kt += 64) {
#pragma unroll
    for (int i = 0; i < 4; ++i) {
      int row = i * 32 + sr;
      int coff = (sc ^ (row & 7)) << 3;
      const u16* ga = A + (size_t)(arow0 + row) * K + kt + coff;
      const u16* gb = B + (size_t)(brow0 + row) * K + kt + coff;
      u16* la = As + i * 2048 + wv * 512;
      u16* lb = Bs + i * 2048 + wv * 512;
      gload16(ga, la);
      gload16(gb, lb);
    }
    __syncthreads();
#pragma unroll
    for (int kk = 0; kk < 2; ++kk) {
      short8 av[4], bv[4];
#pragma unroll
      for (int m = 0; m < 4; ++m) {
        int ra = wr * 64 + m * 16 + li;
        int ca = ((kk << 2) + hk) ^ (ra & 7);
        av[m] = *reinterpret_cast<const short8*>(As + ra * 64 + ca * 8);
      }
#pragma unroll
      for (int n = 0; n < 4; ++n) {
        int rb = wc * 64 + n * 16 + li;
        int cb = ((kk << 2) + hk) ^ (rb & 7);
        bv[n] = *reinterpret_cast<const short8*>(Bs + rb * 64 + cb * 8);
      }
#pragma unroll
      for (int m = 0; m < 4; ++m)
#pragma unroll
        for (int n = 0; n < 4; ++n)
          acc[m][n] = __builtin_amdgcn_mfma_f32_16x16x32_bf16(
              __builtin_bit_cast(bf16x8, av[m]),
              __builtin_bit_cast(bf16x8, bv[n]),
              acc[m][n], 0, 0, 0);
    }
    __syncthreads();
  }
}

// ---------------- sim (R9 structure + R11 fold epilogue) ----------------
__global__ __launch_bounds__(256) void sim_kernel(const u16* __restrict__ Z,
                                                  float* __restrict__ S,
                                                  float* __restrict__ dots)
{
  __shared__ alignas(16) u16 As[128 * 64];
  __shared__ alignas(16) u16 Bs[128 * 64];
  const int bm = (int)blockIdx.x / 16, bn = (int)blockIdx.x % 16;
  f32x4 acc[4][4];
  gemm_core_128(Z, Z, bm * 128, bn * 128, 1024, As, Bs, acc);

  const int t = (int)threadIdx.x;
  const int lane = t & 63, wv = t >> 6;
  const int wr = wv >> 1, wc = wv & 1;
  const int li = lane & 15, hk = lane >> 4;

  float dsum = 0.0f;
#pragma unroll
  for (int m = 0; m < 4; ++m) {
#pragma unroll
    for (int j = 0; j < 4; ++j) {
      int grow = bm * 128 + wr * 64 + m * 16 + hk * 4 + j;
      float s = 0.0f;
#pragma unroll
      for (int n = 0; n < 4; ++n) {
        int gcol = bn * 128 + wc * 64 + n * 16 + li;
        float g = acc[m][n][j];
        float logit = (grow == gcol) ? 10.0f : g * 10.0f;
        float w = (gcol == 0 || gcol == 1023 || gcol == 1024 || gcol == 2047)
                      ? 1.0f : 2.0f;
        s += w * expf(logit);
        if (gcol == grow + 1 && (grow & 1023) != 1023) dsum += g;
      }
      s += __shfl_xor(s, 1); s += __shfl_xor(s, 2);
      s += __shfl_xor(s, 4); s += __shfl_xor(s, 8);
      if (li == 0) atomicAdd(&S[grow], s);
    }
  }
#pragma unroll
  for (int d = 1; d < 64; d <<= 1) dsum += __shfl_xor(dsum, d);
  if (lane == 0) atomicAdd(dots, dsum);
}

// ---------------- fused prep: convert_x(fp8,x8) + transpose W(fp8,x64) + zero S
__global__ void prep_kernel(const float* __restrict__ h1,
                            const float* __restrict__ h2,
                            const float* __restrict__ W1,
                            const float* __restrict__ W2,
                            u8* __restrict__ X8,
                            u8* __restrict__ W1t,
                            u8* __restrict__ W2t,
                            float* __restrict__ S)
{
  __shared__ float tile[32][33];
  int bid = (int)blockIdx.x;
  if (bid < 16384) {
    size_t i4 = ((size_t)bid * 256 + threadIdx.x) * 4;
    const float* src = (i4 < 8388608) ? (h1 + i4) : (h2 + (i4 - 8388608));
    float4 v = *reinterpret_cast<const float4*>(src);
    int lo = __builtin_amdgcn_cvt_pk_fp8_f32(v.x * 8.0f, v.y * 8.0f, 0, 0);
    int all4 = __builtin_amdgcn_cvt_pk_fp8_f32(v.z * 8.0f, v.w * 8.0f, lo, 1);
    *reinterpret_cast<uint32_t*>(X8 + i4) = (uint32_t)all4;
    return;
  }
  bid -= 16384;
  const float* W;
  u8* Wt;
  if (bid < 1024) {
    W = W1; Wt = W1t;
  } else if (bid < 2048) {
    W = W2; Wt = W2t; bid -= 1024;
  } else {
    for (int i = (int)threadIdx.x; i < 2064; i += 256) S[i] = 0.0f;
    return;
  }
  const int bx = bid & 31, by = bid >> 5;
  const int tx = (int)threadIdx.x & 31, ty = (int)threadIdx.x >> 5;
#pragma unroll
  for (int i = 0; i < 4; ++i)
    tile[ty + i * 8][tx] = W[(size_t)(by * 32 + ty + i * 8) * 1024 + bx * 32 + tx];
  __syncthreads();
#pragma unroll
  for (int i = 0; i < 4; ++i)
    Wt[(size_t)(bx * 32 + ty + i * 8) * 1024 + by * 32 + tx] =
        f2fp8(tile[tx][ty + i * 8] * 64.0f);
}

// ---------------- row_normalize: out rows -> bf16 unit rows ----------------
__global__ void row_normalize(const float* __restrict__ out, u16* __restrict__ Z)
{
  const int row = (int)blockIdx.x;   // 0..2047
  const int t = (int)threadIdx.x;    // 256
  const float* src = out + ((row < 1024)
      ? ((size_t)7 * 1048576 + (size_t)row * 1024)
      : ((size_t)8388608 + (size_t)7 * 1048576 + (size_t)(row - 1024) * 1024));
  float4 v = reinterpret_cast<const float4*>(src)[t];
  float ss = v.x * v.x + v.y * v.y + v.z * v.z + v.w * v.w;
#pragma unroll
  for (int d = 1; d < 64; d <<= 1) ss += __shfl_xor(ss, d);
  __shared__ float red[4];
  if ((t & 63) == 0) red[t >> 6] = ss;
  __syncthreads();
  float tot = red[0] + red[1] + red[2] + red[3];
  float inv = 1.0f / fmaxf(sqrtf(tot), 1e-12f);
  u16x4 o;
  o[0] = f2bf(v.x * inv); o[1] = f2bf(v.y * inv);
  o[2] = f2bf(v.z * inv); o[3] = f2bf(v.w * inv);
  reinterpret_cast<u16x4*>(Z + (size_t)row * 1024)[t] = o;
}

__global__ void finalize_kernel(const float* __restrict__ S,
                                const float* __restrict__ dots,
                                float* __restrict__ out_loss)
{
  const int t = (int)threadIdx.x;  // 256
  float acc = 0.0f;
  for (int i = t; i < 2048; i += 256) {
    int tl = i & 1023;
    float w = (tl == 0 || tl == 1023) ? 1.0f : 2.0f;
    acc += w * logf(S[i] - 22026.465794806718f);
  }
  __shared__ float red[256];
  red[t] = acc;
  __syncthreads();
  for (int s2 = 128; s2 > 0; s2 >>= 1) {
    if (t < s2) red[t] += red[t + s2];
    __syncthreads();
  }
  if (t == 0) out_loss[0] = (red[0] - 20.0f * dots[0]) / 4092.0f;
}

extern "C" void kernel_launch(void* const* d_in, const int* in_sizes, int n_in,
                              void* d_out, int out_size, void* d_ws, size_t ws_size,
                              hipStream_t stream)
{
  const float* h1 = (const float*)d_in[0];
  const float* h2 = (const float*)d_in[1];
  const float* W1 = (const float*)d_in[2];
  const float* b1 = (const float*)d_in[3];
  const float* W2 = (const float*)d_in[4];
  const float* b2 = (const float*)d_in[5];
  float* out = (float*)d_out;

  char* ws = (char*)d_ws;
  u8*    X8   = (u8*)ws;                       // 16,777,216 B (fp8, x8)
  u8*    Y18  = (u8*)(ws + 16777216);          // 16,777,216 B (fp8, x8)
  u8*    W1t  = (u8*)(ws + 33554432);          //  1,048,576 B (fp8, x64)
  u8*    W2t  = (u8*)(ws + 34603008);          //  1,048,576 B (fp8, x64)
  u16*   Zb   = (u16*)(ws + 35651584);         //  4,194,304 B (bf16)
  float* S    = (float*)(ws + 39845888);       //      8,192 B (+dots at S[2048])
  float* dots = S + 2048;

  // fused: convert_x (16384 blocks) + transpose W1/W2 (2048) + zero S (1)
  prep_kernel<<<18433, 256, 0, stream>>>(h1, h2, W1, W2, X8, W1t, W2t, S);

  // layer 1: [16384,1024] @ W1 -> relu -> fp8 (256 blocks, 512 thr, MX-fp8)
  gemm_fp8<0><<<256, 512, 0, stream>>>(X8, W1t, b1, Y18, nullptr);
  // layer 2: -> relu -> fp32, transposed write into d_out ([b][t][h])
  gemm_fp8<1><<<256, 512, 0, stream>>>(Y18, W2t, b2, nullptr, out);

  // InfoNCE on last batch row (bf16 128^2 Gram, R9-proven; pairs folded)
  row_normalize<<<2048, 256, 0, stream>>>(out, Zb);
  sim_kernel<<<256, 256, 0, stream>>>(Zb, S, dots);
  finalize_kernel<<<1, 256, 0, stream>>>(S, dots, out + 16777216);
}

// Round 15
// 98.698 us; speedup vs baseline: 1.9612x; 1.1022x over previous
//
#include <hip/hip_runtime.h>
#include <cstdint>
#include <cstddef>

using u16 = unsigned short;
using u8  = unsigned char;
typedef short short8 __attribute__((ext_vector_type(8)));
typedef __bf16 bf16x8 __attribute__((ext_vector_type(8)));
typedef float f32x4 __attribute__((ext_vector_type(4)));
typedef u16 u16x4 __attribute__((ext_vector_type(4)));
typedef int i32x4 __attribute__((ext_vector_type(4)));
typedef int i32x8 __attribute__((ext_vector_type(8)));

__device__ __forceinline__ u16 f2bf(float f) {
  union { float f; uint32_t u; } v; v.f = f;
  uint32_t r = v.u + 0x7FFF + ((v.u >> 16) & 1);
  return (u16)(r >> 16);
}
__device__ __forceinline__ u8 f2fp8(float f) {
  return (u8)(__builtin_amdgcn_cvt_pk_fp8_f32(f, f, 0, 0) & 0xFF);
}

__device__ __forceinline__ void gload16(const void* g, void* l) {
  __builtin_amdgcn_global_load_lds(
      (const __attribute__((address_space(1))) void*)g,
      (__attribute__((address_space(3))) void*)l, 16, 0, 0);
}

// =====================================================================
// MX-fp8 GEMM skeleton (R9/R13, proven ~22us; simple epilogues only —
// complex epilogues on the 128-AGPR accumulator spill, R13 lesson).
// =====================================================================
#define MFMAQ8(M0, N0, AF, BF)                                             \
  {                                                                        \
    _Pragma("unroll") for (int m_ = 0; m_ < 4; ++m_) {                     \
      _Pragma("unroll") for (int n_ = 0; n_ < 2; ++n_) {                   \
        acc[(M0) + m_][(N0) + n_] =                                        \
            __builtin_amdgcn_mfma_scale_f32_16x16x128_f8f6f4(              \
                AF[m_], BF[n_], acc[(M0) + m_][(N0) + n_],                 \
                0, 0, 0, 127, 0, 127);                                     \
      }                                                                    \
    }                                                                      \
  }

__device__ __forceinline__ void fp8_core(
    const u8* __restrict__ A, const u8* __restrict__ Bt,
    int arow0, int brow0, u8* lds, f32x4 (&acc)[8][4],
    int lane, int wid, int wr, int wc, int li)
{
  constexpr int Kb = 1024, NT = 8;
  const int Rl = lane >> 3;
  const int sc16 = ((lane & 7) ^ Rl) << 4;
  const int wid2 = wid * 2;
  const int hk = lane >> 4;
  const int c0b = (((hk << 1) + 0) ^ (li & 7)) << 4;
  const int c1b = (((hk << 1) + 1) ^ (li & 7)) << 4;

  auto STAGE = [&](const u8* G, int growbase, int tau, int ldsoff) {
#pragma unroll
    for (int l = 0; l < 2; ++l) {
      const u8* g = G + (size_t)(growbase + (wid2 + l) * 8 + Rl) * Kb +
                    tau * 128 + sc16;
      gload16(g, lds + ldsoff + (wid2 + l) * 1024);
    }
  };
  auto RD = [&](const u8* base, int row) -> i32x8 {
    const u8* p = base + row * 128;
    i32x4 lo = *reinterpret_cast<const i32x4*>(p + c0b);
    i32x4 hi = *reinterpret_cast<const i32x4*>(p + c1b);
    i32x8 r;
    r[0] = lo[0]; r[1] = lo[1]; r[2] = lo[2]; r[3] = lo[3];
    r[4] = hi[0]; r[5] = hi[1]; r[6] = hi[2]; r[7] = hi[3];
    return r;
  };

  i32x8 aa[4], bb01[2], bb23[2];

  STAGE(Bt, brow0 + 0,   0, 65536 + 0);
  STAGE(Bt, brow0 + 128, 0, 65536 + 16384);
  STAGE(A,  arow0 + 0,   0, 0);
  STAGE(A,  arow0 + 128, 0, 16384);
  STAGE(Bt, brow0 + 0,   1, 65536 + 32768);
  STAGE(Bt, brow0 + 128, 1, 65536 + 32768 + 16384);
  STAGE(A,  arow0 + 0,   1, 32768);
  STAGE(A,  arow0 + 128, 1, 32768 + 16384);
  asm volatile("s_waitcnt vmcnt(8)" ::: "memory");
  __builtin_amdgcn_s_barrier();

  {
    const u8* Ab0 = lds + wr * 16384;
    const u8* Bb0 = lds + 65536 + wc * 8192;
#pragma unroll
    for (int m = 0; m < 4; ++m) aa[m] = RD(Ab0, m * 16 + li);
#pragma unroll
    for (int n = 0; n < 2; ++n) bb01[n] = RD(Bb0, n * 16 + li);
  }

  for (int tau = 0; tau < NT; ++tau) {
    const int cur = tau & 1, nxt = cur ^ 1;
    const u8* Ab  = lds + cur * 32768 + wr * 16384;
    const u8* Bb  = lds + 65536 + cur * 32768 + wc * 8192;
    const u8* Abn = lds + nxt * 32768 + wr * 16384;
    const u8* Bbn = lds + 65536 + nxt * 32768 + wc * 8192;

#pragma unroll
    for (int n = 0; n < 2; ++n) bb23[n] = RD(Bb, 32 + n * 16 + li);
    asm volatile("s_waitcnt lgkmcnt(4)" ::: "memory");
    __builtin_amdgcn_sched_barrier(0);
    __builtin_amdgcn_s_setprio(1);
    MFMAQ8(0, 0, aa, bb01);
    __builtin_amdgcn_s_setprio(0);

    asm volatile("s_waitcnt lgkmcnt(0)" ::: "memory");
    __builtin_amdgcn_sched_barrier(0);
    __builtin_amdgcn_s_setprio(1);
    MFMAQ8(0, 2, aa, bb23);
    __builtin_amdgcn_s_setprio(0);
    __builtin_amdgcn_sched_barrier(0);
#pragma unroll
    for (int m = 0; m < 4; ++m) aa[m] = RD(Ab, (m + 4) * 16 + li);
    __builtin_amdgcn_s_barrier();

    if (tau + 2 < NT) {
      STAGE(Bt, brow0 + 0,   tau + 2, 65536 + cur * 32768);
      STAGE(Bt, brow0 + 128, tau + 2, 65536 + cur * 32768 + 16384);
    }
    asm volatile("s_waitcnt lgkmcnt(0)" ::: "memory");
    __builtin_amdgcn_sched_barrier(0);
    __builtin_amdgcn_s_setprio(1);
    MFMAQ8(4, 2, aa, bb23);
    __builtin_amdgcn_s_setprio(0);
    __builtin_amdgcn_s_barrier();

    if (tau + 2 < NT) {
      STAGE(A, arow0 + 0,   tau + 2, cur * 32768);
      STAGE(A, arow0 + 128, tau + 2, cur * 32768 + 16384);
      asm volatile("s_waitcnt vmcnt(8)" ::: "memory");
    } else if (tau + 1 < NT) {
      asm volatile("s_waitcnt vmcnt(0)" ::: "memory");
    }
    __builtin_amdgcn_s_barrier();
    __builtin_amdgcn_s_setprio(1);
    MFMAQ8(4, 0, aa, bb01);
    __builtin_amdgcn_s_setprio(0);
    __builtin_amdgcn_sched_barrier(0);
    if (tau + 1 < NT) {
#pragma unroll
      for (int m = 0; m < 4; ++m) aa[m] = RD(Abn, m * 16 + li);
#pragma unroll
      for (int n = 0; n < 2; ++n) bb01[n] = RD(Bbn, n * 16 + li);
    }
  }
}

// ---------------- MLP GEMM (fp8): relu(acc/512 + b) ----------------
template <int EPI>
__global__ __launch_bounds__(512, 2) void gemm_fp8(
    const u8* __restrict__ A, const u8* __restrict__ Bt,
    const float* __restrict__ bias,
    u8* __restrict__ C8, float* __restrict__ Cf)
{
  constexpr int N = 1024;
  __shared__ alignas(16) u8 lds[131072];
  const int t = (int)threadIdx.x;
  const int lane = t & 63, wid = t >> 6;
  const int wr = wid >> 2, wc = wid & 3;
  const int li = lane & 15, hk = lane >> 4;

  const int orig = (int)blockIdx.x;
  const int cpx = (int)gridDim.x >> 3;
  const int swz = (orig & 7) * cpx + (orig >> 3);
  const int bm = swz >> 2, bn = swz & 3;
  const int arow0 = bm * 256, brow0 = bn * 256;

  f32x4 acc[8][4];
#pragma unroll
  for (int m = 0; m < 8; ++m)
#pragma unroll
    for (int n = 0; n < 4; ++n)
#pragma unroll
      for (int j = 0; j < 4; ++j) acc[m][n][j] = 0.0f;

  fp8_core(A, Bt, arow0, brow0, lds, acc, lane, wid, wr, wc, li);

#pragma unroll
  for (int m = 0; m < 8; ++m) {
#pragma unroll
    for (int n = 0; n < 4; ++n) {
      const int gcol = brow0 + wc * 64 + n * 16 + li;
      const float bv = bias[gcol];
#pragma unroll
      for (int j = 0; j < 4; ++j) {
        const int grow = arow0 + wr * 128 + m * 16 + hk * 4 + j;
        float v = fmaxf(acc[m][n][j] * 0.001953125f + bv, 0.0f);
        if (EPI == 0) {
          C8[(size_t)grow * N + gcol] = f2fp8(v * 8.0f);
        } else {
          int tensor = grow >> 13, rr = grow & 8191;
          int tt = rr >> 3, b_ = rr & 7;
          Cf[(size_t)tensor * 8388608 + (size_t)b_ * 1048576 +
             (size_t)tt * 1024 + gcol] = v;
        }
      }
    }
  }
}

// =====================================================================
// R15 sim: 128x128 fp8 Gram tile, 4 waves (2x2), 256 threads, NT=8
// (BK=128 fp8 elements = 128B rows -> proven conflict-free geometry;
// half the serial iterations of the 44.4us bf16 version).
// acc[4][4] (64 f32) -> no spill (R13's spill was acc[8][4]+epilogue).
// Z8 = fp8(z*16) -> G = acc/256 (R13-proven precision, absmax 0.078).
// Fused epilogue: S[m] += w*exp(10*G); dots += superdiag.
// =====================================================================
__global__ __launch_bounds__(256) void sim_fp8_128(
    const u8* __restrict__ Z8, float* __restrict__ S, float* __restrict__ dots)
{
  __shared__ alignas(16) u8 As[16384];   // [128][128B]
  __shared__ alignas(16) u8 Bs[16384];
  const int t = (int)threadIdx.x;
  const int lane = t & 63, wv = t >> 6;
  const int wr = wv >> 1, wc = wv & 1;
  const int li = lane & 15, hk = lane >> 4;
  const int sr = t >> 3, sc = t & 7;
  const int bm = (int)blockIdx.x >> 4, bn = (int)blockIdx.x & 15;
  const int arow0 = bm * 128, brow0 = bn * 128;

  const int c0b = (((hk << 1) + 0) ^ (li & 7)) << 4;
  const int c1b = (((hk << 1) + 1) ^ (li & 7)) << 4;

  f32x4 acc[4][4];
#pragma unroll
  for (int m = 0; m < 4; ++m)
#pragma unroll
    for (int n = 0; n < 4; ++n)
#pragma unroll
      for (int j = 0; j < 4; ++j) acc[m][n][j] = 0.0f;

  auto RD = [&](const u8* base, int row) -> i32x8 {
    const u8* p = base + row * 128;
    i32x4 lo = *reinterpret_cast<const i32x4*>(p + c0b);
    i32x4 hi = *reinterpret_cast<const i32x4*>(p + c1b);
    i32x8 r;
    r[0] = lo[0]; r[1] = lo[1]; r[2] = lo[2]; r[3] = lo[3];
    r[4] = hi[0]; r[5] = hi[1]; r[6] = hi[2]; r[7] = hi[3];
    return r;
  };

  for (int tau = 0; tau < 8; ++tau) {
    const int kt = tau * 128;
#pragma unroll
    for (int i = 0; i < 4; ++i) {
      int row = i * 32 + sr;
      int coff = (sc ^ (row & 7)) << 4;  // pre-swizzled source chunk (bytes)
      gload16(Z8 + (size_t)(arow0 + row) * 1024 + kt + coff,
              As + i * 4096 + wv * 1024);
      gload16(Z8 + (size_t)(brow0 + row) * 1024 + kt + coff,
              Bs + i * 4096 + wv * 1024);
    }
    __syncthreads();
    i32x8 av[4], bv[4];
#pragma unroll
    for (int m = 0; m < 4; ++m) av[m] = RD(As, wr * 64 + m * 16 + li);
#pragma unroll
    for (int n = 0; n < 4; ++n) bv[n] = RD(Bs, wc * 64 + n * 16 + li);
#pragma unroll
    for (int m = 0; m < 4; ++m)
#pragma unroll
      for (int n = 0; n < 4; ++n)
        acc[m][n] = __builtin_amdgcn_mfma_scale_f32_16x16x128_f8f6f4(
            av[m], bv[n], acc[m][n], 0, 0, 0, 127, 0, 127);
    __syncthreads();
  }

  float dsum = 0.0f;
#pragma unroll
  for (int m = 0; m < 4; ++m) {
#pragma unroll
    for (int j = 0; j < 4; ++j) {
      int grow = arow0 + wr * 64 + m * 16 + hk * 4 + j;
      float s = 0.0f;
#pragma unroll
      for (int n = 0; n < 4; ++n) {
        int gcol = brow0 + wc * 64 + n * 16 + li;
        float g = acc[m][n][j] * 0.00390625f;   // /256
        float logit = (grow == gcol) ? 10.0f : g * 10.0f;
        float w = (gcol == 0 || gcol == 1023 || gcol == 1024 || gcol == 2047)
                      ? 1.0f : 2.0f;
        s += w * expf(logit);
        if (gcol == grow + 1 && (grow & 1023) != 1023) dsum += g;
      }
      s += __shfl_xor(s, 1); s += __shfl_xor(s, 2);
      s += __shfl_xor(s, 4); s += __shfl_xor(s, 8);
      if (li == 0) atomicAdd(&S[grow], s);
    }
  }
#pragma unroll
  for (int d = 1; d < 64; d <<= 1) dsum += __shfl_xor(dsum, d);
  if (lane == 0) atomicAdd(dots, dsum);
}

// ---------------- fused prep: convert_x(fp8,x8) + transpose W(fp8,x64) + zero S
__global__ void prep_kernel(const float* __restrict__ h1,
                            const float* __restrict__ h2,
                            const float* __restrict__ W1,
                            const float* __restrict__ W2,
                            u8* __restrict__ X8,
                            u8* __restrict__ W1t,
                            u8* __restrict__ W2t,
                            float* __restrict__ S)
{
  __shared__ float tile[32][33];
  int bid = (int)blockIdx.x;
  if (bid < 16384) {
    size_t i4 = ((size_t)bid * 256 + threadIdx.x) * 4;
    const float* src = (i4 < 8388608) ? (h1 + i4) : (h2 + (i4 - 8388608));
    float4 v = *reinterpret_cast<const float4*>(src);
    int lo = __builtin_amdgcn_cvt_pk_fp8_f32(v.x * 8.0f, v.y * 8.0f, 0, 0);
    int all4 = __builtin_amdgcn_cvt_pk_fp8_f32(v.z * 8.0f, v.w * 8.0f, lo, 1);
    *reinterpret_cast<uint32_t*>(X8 + i4) = (uint32_t)all4;
    return;
  }
  bid -= 16384;
  const float* W;
  u8* Wt;
  if (bid < 1024) {
    W = W1; Wt = W1t;
  } else if (bid < 2048) {
    W = W2; Wt = W2t; bid -= 1024;
  } else {
    for (int i = (int)threadIdx.x; i < 2064; i += 256) S[i] = 0.0f;
    return;
  }
  const int bx = bid & 31, by = bid >> 5;
  const int tx = (int)threadIdx.x & 31, ty = (int)threadIdx.x >> 5;
#pragma unroll
  for (int i = 0; i < 4; ++i)
    tile[ty + i * 8][tx] = W[(size_t)(by * 32 + ty + i * 8) * 1024 + bx * 32 + tx];
  __syncthreads();
#pragma unroll
  for (int i = 0; i < 4; ++i)
    Wt[(size_t)(bx * 32 + ty + i * 8) * 1024 + by * 32 + tx] =
        f2fp8(tile[tx][ty + i * 8] * 64.0f);
}

// ---------------- row_normalize: out rows -> fp8 z*16 (R13-proven) ----------------
__global__ void row_normalize(const float* __restrict__ out, u8* __restrict__ Z8)
{
  const int row = (int)blockIdx.x;   // 0..2047
  const int t = (int)threadIdx.x;    // 256
  const float* src = out + ((row < 1024)
      ? ((size_t)7 * 1048576 + (size_t)row * 1024)
      : ((size_t)8388608 + (size_t)7 * 1048576 + (size_t)(row - 1024) * 1024));
  float4 v = reinterpret_cast<const float4*>(src)[t];
  float ss = v.x * v.x + v.y * v.y + v.z * v.z + v.w * v.w;
#pragma unroll
  for (int d = 1; d < 64; d <<= 1) ss += __shfl_xor(ss, d);
  __shared__ float red[4];
  if ((t & 63) == 0) red[t >> 6] = ss;
  __syncthreads();
  float tot = red[0] + red[1] + red[2] + red[3];
  float inv = 16.0f / fmaxf(sqrtf(tot), 1e-12f);   // fp8 scale x16 folded in
  int lo = __builtin_amdgcn_cvt_pk_fp8_f32(v.x * inv, v.y * inv, 0, 0);
  int all4 = __builtin_amdgcn_cvt_pk_fp8_f32(v.z * inv, v.w * inv, lo, 1);
  reinterpret_cast<uint32_t*>(Z8 + (size_t)row * 1024)[t] = (uint32_t)all4;
}

__global__ void finalize_kernel(const float* __restrict__ S,
                                const float* __restrict__ dots,
                                float* __restrict__ out_loss)
{
  const int t = (int)threadIdx.x;  // 256
  float acc = 0.0f;
  for (int i = t; i < 2048; i += 256) {
    int tl = i & 1023;
    float w = (tl == 0 || tl == 1023) ? 1.0f : 2.0f;
    acc += w * logf(S[i] - 22026.465794806718f);
  }
  __shared__ float red[256];
  red[t] = acc;
  __syncthreads();
  for (int s2 = 128; s2 > 0; s2 >>= 1) {
    if (t < s2) red[t] += red[t + s2];
    __syncthreads();
  }
  if (t == 0) out_loss[0] = (red[0] - 20.0f * dots[0]) / 4092.0f;
}

extern "C" void kernel_launch(void* const* d_in, const int* in_sizes, int n_in,
                              void* d_out, int out_size, void* d_ws, size_t ws_size,
                              hipStream_t stream)
{
  const float* h1 = (const float*)d_in[0];
  const float* h2 = (const float*)d_in[1];
  const float* W1 = (const float*)d_in[2];
  const float* b1 = (const float*)d_in[3];
  const float* W2 = (const float*)d_in[4];
  const float* b2 = (const float*)d_in[5];
  float* out = (float*)d_out;

  char* ws = (char*)d_ws;
  u8*    X8   = (u8*)ws;                       // 16,777,216 B (fp8, x8)
  u8*    Y18  = (u8*)(ws + 16777216);          // 16,777,216 B (fp8, x8)
  u8*    W1t  = (u8*)(ws + 33554432);          //  1,048,576 B (fp8, x64)
  u8*    W2t  = (u8*)(ws + 34603008);          //  1,048,576 B (fp8, x64)
  u8*    Z8   = (u8*)(ws + 35651584);          //  2,097,152 B (fp8, x16)
  float* S    = (float*)(ws + 37748736);       //      8,192 B (+dots at S[2048])
  float* dots = S + 2048;

  // fused: convert_x (16384 blocks) + transpose W1/W2 (2048) + zero S (1)
  prep_kernel<<<18433, 256, 0, stream>>>(h1, h2, W1, W2, X8, W1t, W2t, S);

  // layer 1: [16384,1024] @ W1 -> relu -> fp8 (256 blocks, 512 thr, MX-fp8)
  gemm_fp8<0><<<256, 512, 0, stream>>>(X8, W1t, b1, Y18, nullptr);
  // layer 2: -> relu -> fp32, transposed write into d_out ([b][t][h])
  gemm_fp8<1><<<256, 512, 0, stream>>>(Y18, W2t, b2, nullptr, out);

  // InfoNCE on last batch row: fp8 128^2 Gram, NT=8 (half of bf16's 16)
  row_normalize<<<2048, 256, 0, stream>>>(out, Z8);
  sim_fp8_128<<<256, 256, 0, stream>>>(Z8, S, dots);
  finalize_kernel<<<1, 256, 0, stream>>>(S, dots, out + 16777216);
}